// Round 11
// baseline (155.794 us; speedup 1.0000x reference)
//
#include <hip/hip_runtime.h>
#include <hip/hip_bf16.h>
#include <stdint.h>

typedef __bf16 bf16_t;
typedef __bf16 bf16x8 __attribute__((ext_vector_type(8)));
typedef float f32x4 __attribute__((ext_vector_type(4)));

#define DEVI __device__ __forceinline__

constexpr int BB = 2;       // batch
constexpr int SS = 4096;    // seq
constexpr int EE = 1024;    // embed
constexpr int HH = 16;      // heads
constexpr int DD = 64;      // head dim
constexpr int MM = BB * SS; // 8192 token rows

// async global->LDS, 16B per lane; LDS dest must be wave-uniform base (HW adds lane*16)
DEVI void gload16(const void* g, void* l) {
  __builtin_amdgcn_global_load_lds(
      (const __attribute__((address_space(1))) void*)g,
      (__attribute__((address_space(3))) void*)l, 16, 0, 0);
}

// ---------------- f32 -> bf16 convert (vectorized 8/thread) ----------------
__global__ void cvt_kernel(const float* __restrict__ in, bf16_t* __restrict__ out, int n8) {
  int i = blockIdx.x * 256 + threadIdx.x;
  if (i >= n8) return;
  const float* p = in + (size_t)i * 8;
  bf16x8 o;
#pragma unroll
  for (int j = 0; j < 8; ++j) o[j] = (bf16_t)p[j];
  *(bf16x8*)(out + (size_t)i * 8) = o;
}

// ---------------- weight transpose + cvt: W[k][n] f32 -> WT[n][k] bf16 ----------------
__global__ void wt_kernel(const float* __restrict__ w0, const float* __restrict__ w1,
                          const float* __restrict__ w2, const float* __restrict__ w3,
                          const float* __restrict__ w4, bf16_t* __restrict__ out) {
  __shared__ float tile[32][33];
  const float* Wsel = blockIdx.z == 0 ? w0 : blockIdx.z == 1 ? w1 :
                      blockIdx.z == 2 ? w2 : blockIdx.z == 3 ? w3 : w4;
  bf16_t* O = out + (size_t)blockIdx.z * EE * EE;
  int n0 = blockIdx.x * 32, k0 = blockIdx.y * 32;
  int tx = threadIdx.x & 31, ty = threadIdx.x >> 5;
#pragma unroll
  for (int i = 0; i < 4; ++i)
    tile[ty + i * 8][tx] = Wsel[(size_t)(k0 + ty + i * 8) * EE + n0 + tx];
  __syncthreads();
#pragma unroll
  for (int i = 0; i < 4; ++i)
    O[(size_t)(n0 + ty + i * 8) * EE + k0 + tx] = (bf16_t)tile[tx][ty + i * 8];
}

// ---------------- CSK: rope-ordered bf16 cos/sin table [s][c:4][32] ----------------
// per (s, octet c): [cos d=c*8.. | sin d=c*8.. | cos d=32+c*8.. | sin d=32+c*8..]
__global__ void csk_kernel(const float* __restrict__ cosp, const float* __restrict__ sinp,
                           bf16_t* __restrict__ csk) {
  int i = blockIdx.x * 256 + threadIdx.x;  // 4096*128
  int s = i >> 7, idx = i & 127;
  int c = idx >> 5, j = idx & 31;
  int part = j >> 3, jj = j & 7;
  int d = c * 8 + jj + ((part >= 2) ? 32 : 0);
  const float* src = (part & 1) ? sinp : cosp;
  csk[i] = (bf16_t)src[s * 64 + d];
}

// ---------------- GEMM: C[M][N] = A[M][K] @ Bt[N][K]^T, 128x128 tile, BK=64 ----------------
// EXACT r1 form (measured 81.9-83.3 us / VGPR 80 / FETCH 56.4MB): runtime Kdim,
// per-element widx epilogue. FROZEN — r3-r7 "improvements" all measured 93-100 us.
template <int MODE>
__global__ __launch_bounds__(256) void gemm_bt(const bf16_t* __restrict__ A,
                                               const bf16_t* __restrict__ Bt,
                                               void* __restrict__ Cout, int Kdim) {
  __shared__ bf16_t Al[128 * 64];
  __shared__ bf16_t Bl[128 * 64];
  const int m0 = blockIdx.x * 128;
  const int n0 = blockIdx.y * 128;
  const int tid = threadIdx.x;
  const int wv = tid >> 6, ln = tid & 63;
  const int wm = wv >> 1, wn = wv & 1;
  f32x4 acc[4][4] = {};

  for (int k0 = 0; k0 < Kdim; k0 += 64) {
    __syncthreads();  // prior iter's LDS readers done before overwrite
#pragma unroll
    for (int i = 0; i < 4; ++i) {
      int slot = i * 256 + wv * 64 + ln;  // 16B slots, 8 per 128B row
      int r = slot >> 3, c = slot & 7;
      int cs = c ^ (r & 7);  // inverse-swizzled source chunk (linear LDS dest)
      gload16(A + (size_t)(m0 + r) * Kdim + k0 + cs * 8, Al + (size_t)(i * 256 + wv * 64) * 8);
      gload16(Bt + (size_t)(n0 + r) * Kdim + k0 + cs * 8, Bl + (size_t)(i * 256 + wv * 64) * 8);
    }
    __syncthreads();  // compiler drains vmcnt(0) before barrier
#pragma unroll
    for (int kk = 0; kk < 2; ++kk) {
      bf16x8 af[4], bfr[4];
#pragma unroll
      for (int mi = 0; mi < 4; ++mi) {
        int row = wm * 64 + mi * 16 + (ln & 15);
        int ch = (kk * 4 + (ln >> 4)) ^ (row & 7);
        af[mi] = *(const bf16x8*)(Al + row * 64 + ch * 8);
      }
#pragma unroll
      for (int ni = 0; ni < 4; ++ni) {
        int row = wn * 64 + ni * 16 + (ln & 15);
        int ch = (kk * 4 + (ln >> 4)) ^ (row & 7);
        bfr[ni] = *(const bf16x8*)(Bl + row * 64 + ch * 8);
      }
#pragma unroll
      for (int mi = 0; mi < 4; ++mi)
#pragma unroll
        for (int ni = 0; ni < 4; ++ni)
          acc[mi][ni] = __builtin_amdgcn_mfma_f32_16x16x32_bf16(af[mi], bfr[ni], acc[mi][ni], 0, 0, 0);
    }
  }

  if (MODE == 0) {
    bf16_t* Obase = (bf16_t*)Cout;
#pragma unroll
    for (int mi = 0; mi < 4; ++mi) {
#pragma unroll
      for (int ni = 0; ni < 4; ++ni) {
        int row = m0 + wm * 64 + mi * 16 + ((ln >> 4) << 2);  // + reg
        int col = n0 + wn * 64 + ni * 16 + (ln & 15);
        int widx = col >> 10, ncol = col & 1023;
        bf16_t* W = Obase + (size_t)widx * MM * EE;
        if (widx == 2) {  // V: write transposed [B][H][D][S]
          int h = ncol >> 6, d = ncol & 63;
          int b = row >> 12, s = row & (SS - 1);
          bf16_t* p = W + (((size_t)b * HH + h) * DD + d) * SS + s;
#pragma unroll
          for (int r = 0; r < 4; ++r) p[r] = (bf16_t)acc[mi][ni][r];
        } else {
          bf16_t* p = W + (size_t)row * EE + ncol;
#pragma unroll
          for (int r = 0; r < 4; ++r) p[(size_t)r * EE] = (bf16_t)acc[mi][ni][r];
        }
      }
    }
  } else {
    float* O = (float*)Cout;
#pragma unroll
    for (int mi = 0; mi < 4; ++mi)
#pragma unroll
      for (int ni = 0; ni < 4; ++ni) {
        int row = m0 + wm * 64 + mi * 16 + ((ln >> 4) << 2);
        int col = n0 + wn * 64 + ni * 16 + (ln & 15);
#pragma unroll
        for (int r = 0; r < 4; ++r) O[(size_t)(row + r) * EE + col] = acc[mi][ni][r];
      }
  }
}

// ---------------- block-diagonal attention + fused RoPE + fused sigmoid gate ----------------
// r11: r10 split-wait pipeline with the rope hi-part operand swap FIXED:
//   ohi = hi*cos_hi + lo*sin_hi  (CSK idx: [2]=cos_hi, [3]=sin_hi — r10 had 3/2 swapped)
__global__ __launch_bounds__(256, 2) void attn_kernel(const bf16_t* __restrict__ Q,
                                                      const bf16_t* __restrict__ Kc,
                                                      const bf16_t* __restrict__ Vt,
                                                      const bf16_t* __restrict__ G,
                                                      const bf16_t* __restrict__ CSK,
                                                      bf16_t* __restrict__ AO) {
  __shared__ bf16_t Kl[256 * 64];   // 32KB: K rows (roped); reused as f32 o-transpose buffer
  __shared__ bf16_t Vl[64 * 256];   // 32KB: V^T [d][s], chunk-swizzle c^((d&7)<<2)
  __shared__ bf16_t Pl[4][32 * 64]; // 16KB: per-wave P chunk; head reused for lr
  const int id = blockIdx.x;
  const int swz = (id & 7) * 128 + (id >> 3);  // XCD swizzle: half-block pairs share an XCD
  const int half = swz & 1, ab = swz >> 1;
  const int h = ab & 15, sb = (ab >> 4) & 15, b = ab >> 8;
  const int tid = threadIdx.x, wv = tid >> 6, ln = tid & 63;
  const int qs0 = sb * 256 + half * 128 + wv * 32;  // this wave's 32 q-rows (seq index)

  // ======== (a) register loads: Q frags, Q-CSK, K-rope CSK, G — ISSUED FIRST ========
  const int d0 = (ln >> 4) << 3;
  bf16x8 qraw[2][2], qcs[2][4];
#pragma unroll
  for (int mi = 0; mi < 2; ++mi) {
    int qs = qs0 + mi * 16 + (ln & 15);
    const bf16_t* qp = Q + ((size_t)b * SS + qs) * EE + h * DD;
    qraw[mi][0] = *(const bf16x8*)(qp + d0);
    qraw[mi][1] = *(const bf16x8*)(qp + 32 + d0);
    const bf16_t* cp = CSK + (size_t)qs * 128 + (d0 >> 3) * 32;
#pragma unroll
    for (int t = 0; t < 4; ++t) qcs[mi][t] = *(const bf16x8*)(cp + t * 8);
  }
  const int kcol = tid & 3;  // K-rope octet this thread handles
  bf16x8 kcs[4][4];
#pragma unroll
  for (int rr = 0; rr < 4; ++rr) {
    int ks = sb * 256 + rr * 64 + (tid >> 2);
    const bf16_t* cp = CSK + (size_t)ks * 128 + kcol * 32;
#pragma unroll
    for (int t = 0; t < 4; ++t) kcs[rr][t] = *(const bf16x8*)(cp + t * 8);
  }
  const int erow = ln >> 1, ehf = ln & 1;  // epilogue row / 32-col half
  const int em = b * SS + qs0 + erow;
  bf16x8 gpre[4];
  {
    const bf16_t* gp = G + (size_t)em * EE + h * DD + ehf * 32;
#pragma unroll
    for (int i = 0; i < 4; ++i) gpre[i] = *(const bf16x8*)(gp + i * 8);
  }
  __builtin_amdgcn_sched_barrier(0);

  // ======== (b) K staging: 8 gload16/thread ========
  {
    const bf16_t* Kbase = Kc + ((size_t)b * SS + sb * 256) * EE + h * DD;
    int kr = wv * 8 + (ln >> 3), kc8 = ln & 7;
#pragma unroll
    for (int g = 0; g < 8; ++g) {
      int r = g * 32 + kr, cs = kc8 ^ (r & 7);
      gload16(Kbase + (size_t)r * EE + cs * 8, &Kl[g * 2048 + wv * 512]);
    }
  }
  __builtin_amdgcn_sched_barrier(0);

  // ======== (c) V staging: 8 gload16/thread (youngest — stays in flight longest) ========
  {
    const bf16_t* Vbase = Vt + ((size_t)b * HH + h) * DD * SS + sb * 256;
    int vr = wv * 2 + (ln >> 5), vc = ln & 31;
#pragma unroll
    for (int g = 0; g < 8; ++g) {
      int r = g * 8 + vr, cs = vc ^ ((r & 7) << 2);
      gload16(Vbase + (size_t)r * SS + cs * 8, &Vl[g * 2048 + wv * 512]);
    }
  }
  __builtin_amdgcn_sched_barrier(0);

  // ======== (d) Q-rope in registers (compiler waits only on reg loads) ========
  bf16x8 qf[2][2];
#pragma unroll
  for (int mi = 0; mi < 2; ++mi)
#pragma unroll
    for (int j = 0; j < 8; ++j) {
      float lo = (float)qraw[mi][0][j], hi = (float)qraw[mi][1][j];
      qf[mi][0][j] = (bf16_t)(lo * (float)qcs[mi][0][j] - hi * (float)qcs[mi][1][j]);
      qf[mi][1][j] = (bf16_t)(hi * (float)qcs[mi][2][j] + lo * (float)qcs[mi][3][j]);
    }

  // ======== (e) K landed (V still in flight: youngest 8) ========
  asm volatile("s_waitcnt vmcnt(8)" ::: "memory");
  __builtin_amdgcn_s_barrier();
  __builtin_amdgcn_sched_barrier(0);

  // ======== (f) K-rope in LDS: 4 rows/thread, octet pair d <-> d+32 ========
#pragma unroll
  for (int rr = 0; rr < 4; ++rr) {
    int r_ = rr * 64 + (tid >> 2);
    int chl = ((kcol ^ (r_ & 7)) << 3), chh = (((kcol ^ 4) ^ (r_ & 7)) << 3);
    bf16x8 lo8 = *(bf16x8*)&Kl[r_ * 64 + chl];
    bf16x8 hi8 = *(bf16x8*)&Kl[r_ * 64 + chh];
    bf16x8 olo, ohi;
#pragma unroll
    for (int j = 0; j < 8; ++j) {
      float lo = (float)lo8[j], hi = (float)hi8[j];
      olo[j] = (bf16_t)(lo * (float)kcs[rr][0][j] - hi * (float)kcs[rr][1][j]);
      ohi[j] = (bf16_t)(hi * (float)kcs[rr][2][j] + lo * (float)kcs[rr][3][j]);
    }
    *(bf16x8*)&Kl[r_ * 64 + chl] = olo;
    *(bf16x8*)&Kl[r_ * 64 + chh] = ohi;
  }

  // ======== (g) roped K visible (LDS only — vmcnt untouched, V still flying) ========
  asm volatile("s_waitcnt lgkmcnt(0)" ::: "memory");
  __builtin_amdgcn_s_barrier();
  __builtin_amdgcn_sched_barrier(0);

  // ======== (h) QK^T: full S[32q][256k] in registers + exact softmax ========
  f32x4 sc[2][16];
#pragma unroll
  for (int mi = 0; mi < 2; ++mi)
#pragma unroll
    for (int ni = 0; ni < 16; ++ni) sc[mi][ni] = f32x4{0.f, 0.f, 0.f, 0.f};
  __builtin_amdgcn_s_setprio(1);
#pragma unroll
  for (int kk = 0; kk < 2; ++kk) {
#pragma unroll
    for (int ni = 0; ni < 16; ++ni) {
      int row = ni * 16 + (ln & 15);
      int ch = (kk * 4 + (ln >> 4)) ^ (row & 7);
      bf16x8 kf = *(const bf16x8*)(&Kl[row * 64 + ch * 8]);
#pragma unroll
      for (int mi = 0; mi < 2; ++mi)
        sc[mi][ni] = __builtin_amdgcn_mfma_f32_16x16x32_bf16(qf[mi][kk], kf, sc[mi][ni], 0, 0, 0);
    }
  }
  __builtin_amdgcn_s_setprio(0);

  float lr[2][4];
#pragma unroll
  for (int mi = 0; mi < 2; ++mi) {
#pragma unroll
    for (int r = 0; r < 4; ++r) {
      float mx = -1e30f;
#pragma unroll
      for (int ni = 0; ni < 16; ++ni) mx = fmaxf(mx, sc[mi][ni][r] * 0.125f);
#pragma unroll
      for (int d = 1; d < 16; d <<= 1) mx = fmaxf(mx, __shfl_xor(mx, d));
      float rs = 0.f;
#pragma unroll
      for (int ni = 0; ni < 16; ++ni) {
        float p = __expf(sc[mi][ni][r] * 0.125f - mx);
        sc[mi][ni][r] = p;
        rs += p;
      }
#pragma unroll
      for (int d = 1; d < 16; d <<= 1) rs += __shfl_xor(rs, d);
      lr[mi][r] = rs;
    }
  }

  // ======== (i) V landed ========
  asm volatile("s_waitcnt vmcnt(0)" ::: "memory");
  __builtin_amdgcn_s_barrier();
  __builtin_amdgcn_sched_barrier(0);

  // ======== (j) PV: per 64-k chunk through per-wave P-LDS ========
  f32x4 o[2][4] = {};
  bf16_t* P = Pl[wv];
#pragma unroll
  for (int kc = 0; kc < 4; ++kc) {
#pragma unroll
    for (int mi = 0; mi < 2; ++mi)
#pragma unroll
      for (int nq = 0; nq < 4; ++nq)
#pragma unroll
        for (int r = 0; r < 4; ++r) {
          int row = mi * 16 + ((ln >> 4) << 2) + r;
          int col = nq * 16 + (ln & 15);
          P[row * 64 + (col ^ ((row & 7) << 3))] = (bf16_t)sc[mi][kc * 4 + nq][r];
        }
    __builtin_amdgcn_s_setprio(1);
#pragma unroll
    for (int kk = 0; kk < 2; ++kk) {
      bf16x8 pf[2], vf[4];
#pragma unroll
      for (int mi = 0; mi < 2; ++mi) {
        int row = mi * 16 + (ln & 15);
        int ch = (kk * 4 + (ln >> 4)) ^ (row & 7);
        pf[mi] = *(const bf16x8*)(P + row * 64 + ch * 8);
      }
#pragma unroll
      for (int nd = 0; nd < 4; ++nd) {
        int d = nd * 16 + (ln & 15);
        int c = (kc * 8 + kk * 4 + (ln >> 4)) ^ ((d & 7) << 2);
        vf[nd] = *(const bf16x8*)(&Vl[d * 256 + c * 8]);
      }
#pragma unroll
      for (int mi = 0; mi < 2; ++mi)
#pragma unroll
        for (int nd = 0; nd < 4; ++nd)
          o[mi][nd] = __builtin_amdgcn_mfma_f32_16x16x32_bf16(pf[mi], vf[nd], o[mi][nd], 0, 0, 0);
    }
    __builtin_amdgcn_s_setprio(0);
  }

  // ======== (k) epilogue: transpose o through freed Kl; vectorized gate+store ========
  __syncthreads();  // all waves past QK/PV -> Kl safe to overwrite
  float* lrT = (float*)Pl[wv];
  if ((ln & 15) == 0) {
#pragma unroll
    for (int mi = 0; mi < 2; ++mi)
#pragma unroll
      for (int r = 0; r < 4; ++r)
        lrT[mi * 16 + ((ln >> 4) << 2) + r] = lr[mi][r];
  }
  float* T = (float*)Kl + wv * 2048;
#pragma unroll
  for (int mi = 0; mi < 2; ++mi)
#pragma unroll
    for (int nd = 0; nd < 4; ++nd)
#pragma unroll
      for (int r = 0; r < 4; ++r) {
        int row = mi * 16 + ((ln >> 4) << 2) + r;
        int col = nd * 16 + (ln & 15);
        int c = col >> 2;
        T[row * 64 + ((c ^ (row & 7)) << 2) + (col & 3)] = o[mi][nd][r];
      }
  {
    float inv = 1.f / lrT[erow];
    f32x4 ov[8];
#pragma unroll
    for (int j = 0; j < 8; ++j) {
      int c = ehf * 8 + j;
      ov[j] = *(const f32x4*)&T[erow * 64 + ((c ^ (erow & 7)) << 2)];
    }
    bf16_t* ap = AO + (size_t)em * EE + h * DD + ehf * 32;
#pragma unroll
    for (int i = 0; i < 4; ++i) {
      bf16x8 outv;
#pragma unroll
      for (int j2 = 0; j2 < 8; ++j2) {
        float gv = (float)gpre[i][j2];
        float sig = 1.f / (1.f + __expf(-gv));
        outv[j2] = (bf16_t)(ov[i * 2 + (j2 >> 2)][j2 & 3] * inv * sig);
      }
      *(bf16x8*)(ap + i * 8) = outv;
    }
  }
}

extern "C" void kernel_launch(void* const* d_in, const int* in_sizes, int n_in,
                              void* d_out, int out_size, void* d_ws, size_t ws_size,
                              hipStream_t stream) {
  const float* x = (const float*)d_in[0];
  const float* Wq = (const float*)d_in[1];
  const float* Wk = (const float*)d_in[2];
  const float* Wv = (const float*)d_in[3];
  const float* Wg = (const float*)d_in[4];
  const float* Wo = (const float*)d_in[5];
  const float* cosp = (const float*)d_in[6];
  const float* sinp = (const float*)d_in[7];
  float* out = (float*)d_out;

  char* ws = (char*)d_ws;
  bf16_t* XB = (bf16_t*)(ws);                       // 16MB: x bf16; reused as gated AO
  bf16_t* WT = (bf16_t*)(ws + (16ll << 20));        // 10MB: [5][1024][1024] W^T bf16 (q,k,v,g,o)
  bf16_t* QB = (bf16_t*)(ws + (26ll << 20));        // 16MB: Q (unroped)
  bf16_t* KB = (bf16_t*)(ws + (42ll << 20));        // 16MB: K (unroped)
  bf16_t* VT = (bf16_t*)(ws + (58ll << 20));        // 16MB: V transposed [B][H][D][S]
  bf16_t* GB = (bf16_t*)(ws + (74ll << 20));        // 16MB: gate
  bf16_t* CK = (bf16_t*)(ws + (90ll << 20));        // 1MB: CSK rope table
  bf16_t* AO = XB;                                  // gated attention output reuses XB region

  const int n8 = MM * EE / 8;  // 1048576
  cvt_kernel<<<n8 / 256, 256, 0, stream>>>(x, XB, n8);
  wt_kernel<<<dim3(32, 32, 5), 256, 0, stream>>>(Wq, Wk, Wv, Wg, Wo, WT);
  csk_kernel<<<(SS * 128) / 256, 256, 0, stream>>>(cosp, sinp, CK);
  gemm_bt<0><<<dim3(MM / 128, 4 * EE / 128), 256, 0, stream>>>(XB, WT, QB, EE);
  attn_kernel<<<1024, 256, 0, stream>>>(QB, KB, VT, GB, CK, AO);
  gemm_bt<1><<<dim3(MM / 128, EE / 128), 256, 0, stream>>>(AO, WT + (size_t)4 * EE * EE, out, EE);
}

// Round 12
// 153.782 us; speedup vs baseline: 1.0131x; 1.0131x over previous
//
#include <hip/hip_runtime.h>
#include <hip/hip_bf16.h>
#include <stdint.h>

typedef __bf16 bf16_t;
typedef __bf16 bf16x8 __attribute__((ext_vector_type(8)));
typedef float f32x4 __attribute__((ext_vector_type(4)));

#define DEVI __device__ __forceinline__

constexpr int BB = 2;       // batch
constexpr int SS = 4096;    // seq
constexpr int EE = 1024;    // embed
constexpr int HH = 16;      // heads
constexpr int DD = 64;      // head dim
constexpr int MM = BB * SS; // 8192 token rows

// async global->LDS, 16B per lane; LDS dest must be wave-uniform base (HW adds lane*16)
DEVI void gload16(const void* g, void* l) {
  __builtin_amdgcn_global_load_lds(
      (const __attribute__((address_space(1))) void*)g,
      (__attribute__((address_space(3))) void*)l, 16, 0, 0);
}

// ---------------- prep: fused x->bf16 cvt (blocks 0..4095) + W transpose (4096..9215) ----------------
__global__ void prep_kernel(const float* __restrict__ x, bf16_t* __restrict__ xb,
                            const float* __restrict__ w0, const float* __restrict__ w1,
                            const float* __restrict__ w2, const float* __restrict__ w3,
                            const float* __restrict__ w4, bf16_t* __restrict__ wt) {
  __shared__ float tile[32][33];
  if (blockIdx.x < 4096) {
    int i = blockIdx.x * 256 + threadIdx.x;  // n8 = 1048576 elements of 8
    const float* p = x + (size_t)i * 8;
    bf16x8 o;
#pragma unroll
    for (int j = 0; j < 8; ++j) o[j] = (bf16_t)p[j];
    *(bf16x8*)(xb + (size_t)i * 8) = o;
  } else {
    int idx = blockIdx.x - 4096;
    int z = idx >> 10, rem = idx & 1023;
    int n0 = (rem & 31) * 32, k0 = (rem >> 5) * 32;
    const float* Wsel = z == 0 ? w0 : z == 1 ? w1 : z == 2 ? w2 : z == 3 ? w3 : w4;
    bf16_t* O = wt + (size_t)z * EE * EE;
    int tx = threadIdx.x & 31, ty = threadIdx.x >> 5;
#pragma unroll
    for (int i = 0; i < 4; ++i)
      tile[ty + i * 8][tx] = Wsel[(size_t)(k0 + ty + i * 8) * EE + n0 + tx];
    __syncthreads();
#pragma unroll
    for (int i = 0; i < 4; ++i)
      O[(size_t)(n0 + ty + i * 8) * EE + k0 + tx] = (bf16_t)tile[tx][ty + i * 8];
  }
}

// ---------------- GEMM: C[M][N] = A[M][K] @ Bt[N][K]^T, 128x128 tile, BK=64 ----------------
// EXACT r1 form (measured 81.9-83.3 us / VGPR 80 / FETCH 56.4MB): runtime Kdim,
// per-element widx epilogue. FROZEN — r3-r7 "improvements" all measured 93-100 us.
template <int MODE>
__global__ __launch_bounds__(256) void gemm_bt(const bf16_t* __restrict__ A,
                                               const bf16_t* __restrict__ Bt,
                                               void* __restrict__ Cout, int Kdim) {
  __shared__ bf16_t Al[128 * 64];
  __shared__ bf16_t Bl[128 * 64];
  const int m0 = blockIdx.x * 128;
  const int n0 = blockIdx.y * 128;
  const int tid = threadIdx.x;
  const int wv = tid >> 6, ln = tid & 63;
  const int wm = wv >> 1, wn = wv & 1;
  f32x4 acc[4][4] = {};

  for (int k0 = 0; k0 < Kdim; k0 += 64) {
    __syncthreads();  // prior iter's LDS readers done before overwrite
#pragma unroll
    for (int i = 0; i < 4; ++i) {
      int slot = i * 256 + wv * 64 + ln;  // 16B slots, 8 per 128B row
      int r = slot >> 3, c = slot & 7;
      int cs = c ^ (r & 7);  // inverse-swizzled source chunk (linear LDS dest)
      gload16(A + (size_t)(m0 + r) * Kdim + k0 + cs * 8, Al + (size_t)(i * 256 + wv * 64) * 8);
      gload16(Bt + (size_t)(n0 + r) * Kdim + k0 + cs * 8, Bl + (size_t)(i * 256 + wv * 64) * 8);
    }
    __syncthreads();  // compiler drains vmcnt(0) before barrier
#pragma unroll
    for (int kk = 0; kk < 2; ++kk) {
      bf16x8 af[4], bfr[4];
#pragma unroll
      for (int mi = 0; mi < 4; ++mi) {
        int row = wm * 64 + mi * 16 + (ln & 15);
        int ch = (kk * 4 + (ln >> 4)) ^ (row & 7);
        af[mi] = *(const bf16x8*)(Al + row * 64 + ch * 8);
      }
#pragma unroll
      for (int ni = 0; ni < 4; ++ni) {
        int row = wn * 64 + ni * 16 + (ln & 15);
        int ch = (kk * 4 + (ln >> 4)) ^ (row & 7);
        bfr[ni] = *(const bf16x8*)(Bl + row * 64 + ch * 8);
      }
#pragma unroll
      for (int mi = 0; mi < 4; ++mi)
#pragma unroll
        for (int ni = 0; ni < 4; ++ni)
          acc[mi][ni] = __builtin_amdgcn_mfma_f32_16x16x32_bf16(af[mi], bfr[ni], acc[mi][ni], 0, 0, 0);
    }
  }

  if (MODE == 0) {
    bf16_t* Obase = (bf16_t*)Cout;
#pragma unroll
    for (int mi = 0; mi < 4; ++mi) {
#pragma unroll
      for (int ni = 0; ni < 4; ++ni) {
        int row = m0 + wm * 64 + mi * 16 + ((ln >> 4) << 2);  // + reg
        int col = n0 + wn * 64 + ni * 16 + (ln & 15);
        int widx = col >> 10, ncol = col & 1023;
        bf16_t* W = Obase + (size_t)widx * MM * EE;
        if (widx == 2) {  // V: write transposed [B][H][D][S]
          int h = ncol >> 6, d = ncol & 63;
          int b = row >> 12, s = row & (SS - 1);
          bf16_t* p = W + (((size_t)b * HH + h) * DD + d) * SS + s;
#pragma unroll
          for (int r = 0; r < 4; ++r) p[r] = (bf16_t)acc[mi][ni][r];
        } else {
          bf16_t* p = W + (size_t)row * EE + ncol;
#pragma unroll
          for (int r = 0; r < 4; ++r) p[(size_t)r * EE] = (bf16_t)acc[mi][ni][r];
        }
      }
    }
  } else {
    float* O = (float*)Cout;
#pragma unroll
    for (int mi = 0; mi < 4; ++mi)
#pragma unroll
      for (int ni = 0; ni < 4; ++ni) {
        int row = m0 + wm * 64 + mi * 16 + ((ln >> 4) << 2);
        int col = n0 + wn * 64 + ni * 16 + (ln & 15);
#pragma unroll
        for (int r = 0; r < 4; ++r) O[(size_t)(row + r) * EE + col] = acc[mi][ni][r];
      }
  }
}

// ---------------- block-diagonal attention + fused RoPE + fused sigmoid gate ----------------
// r12 = r9 exact (best measured: total 155.0, absmax 0.0156): full 256-key staging,
// f32 cos/sin, G/Q prefetch before first sync, exact softmax, PV via per-wave P-LDS,
// vectorized epilogue via o-transpose through freed Kl.
__global__ __launch_bounds__(256, 2) void attn_kernel(const bf16_t* __restrict__ Q,
                                                      const bf16_t* __restrict__ Kc,
                                                      const bf16_t* __restrict__ Vt,
                                                      const bf16_t* __restrict__ G,
                                                      const float* __restrict__ cosp,
                                                      const float* __restrict__ sinp,
                                                      bf16_t* __restrict__ AO) {
  __shared__ bf16_t Kl[256 * 64];   // 32KB: K rows (roped); reused as f32 o-transpose buffer
  __shared__ bf16_t Vl[64 * 256];   // 32KB: V^T [d][s], chunk-swizzle c^((d&7)<<2)
  __shared__ bf16_t Pl[4][32 * 64]; // 16KB: per-wave P chunk; head 128B reused for lr
  const int id = blockIdx.x;
  const int swz = (id & 7) * 128 + (id >> 3);  // XCD swizzle: half-block pairs share an XCD
  const int half = swz & 1, ab = swz >> 1;
  const int h = ab & 15, sb = (ab >> 4) & 15, b = ab >> 8;
  const int tid = threadIdx.x, wv = tid >> 6, ln = tid & 63;
  const int qs0 = sb * 256 + half * 128 + wv * 32;  // this wave's 32 q-rows (seq index)

  // ---- stage full K (8 groups) + full V^T (8 groups): 16 gload16/thread
  {
    const bf16_t* Kbase = Kc + ((size_t)b * SS + sb * 256) * EE + h * DD;
    int kr = wv * 8 + (ln >> 3), kc8 = ln & 7;
#pragma unroll
    for (int g = 0; g < 8; ++g) {
      int r = g * 32 + kr, cs = kc8 ^ (r & 7);
      gload16(Kbase + (size_t)r * EE + cs * 8, &Kl[g * 2048 + wv * 512]);
    }
    const bf16_t* Vbase = Vt + ((size_t)b * HH + h) * DD * SS + sb * 256;
    int vr = wv * 2 + (ln >> 5), vc = ln & 31;
#pragma unroll
    for (int g = 0; g < 8; ++g) {
      int r = g * 8 + vr, cs = vc ^ ((r & 7) << 2);
      gload16(Vbase + (size_t)r * SS + cs * 8, &Vl[g * 2048 + wv * 512]);
    }
  }

  // ---- prefetch G for the post-transpose epilogue (issued under staging latency)
  const int erow = ln >> 1, ehf = ln & 1;           // lane's epilogue row / 32-col half
  const int em = b * SS + qs0 + erow;               // global token row
  bf16x8 gpre[4];
  {
    const bf16_t* gp = G + (size_t)em * EE + h * DD + ehf * 32;
#pragma unroll
    for (int i = 0; i < 4; ++i) gpre[i] = *(const bf16x8*)(gp + i * 8);
  }

  // ---- Q fragments + cos/sin loads (issued before first sync; compute after)
  bf16x8 qraw[2][2];
  float cl[2][8], sl[2][8], chv[2][8], shv[2][8];
  const int d0 = (ln >> 4) << 3;
#pragma unroll
  for (int mi = 0; mi < 2; ++mi) {
    int qs = qs0 + mi * 16 + (ln & 15);
    const bf16_t* qp = Q + ((size_t)b * SS + qs) * EE + h * DD;
    qraw[mi][0] = *(const bf16x8*)(qp + d0);
    qraw[mi][1] = *(const bf16x8*)(qp + 32 + d0);
    *(f32x4*)&cl[mi][0] = *(const f32x4*)&cosp[qs * DD + d0];
    *(f32x4*)&cl[mi][4] = *(const f32x4*)&cosp[qs * DD + d0 + 4];
    *(f32x4*)&chv[mi][0] = *(const f32x4*)&cosp[qs * DD + d0 + 32];
    *(f32x4*)&chv[mi][4] = *(const f32x4*)&cosp[qs * DD + d0 + 36];
    *(f32x4*)&sl[mi][0] = *(const f32x4*)&sinp[qs * DD + d0];
    *(f32x4*)&sl[mi][4] = *(const f32x4*)&sinp[qs * DD + d0 + 4];
    *(f32x4*)&shv[mi][0] = *(const f32x4*)&sinp[qs * DD + d0 + 32];
    *(f32x4*)&shv[mi][4] = *(const f32x4*)&sinp[qs * DD + d0 + 36];
  }
  __syncthreads();  // drains all gloads (staging) + register loads

  // ---- Q RoPE in registers
  bf16x8 qf[2][2];
#pragma unroll
  for (int mi = 0; mi < 2; ++mi)
#pragma unroll
    for (int j = 0; j < 8; ++j) {
      float lo = (float)qraw[mi][0][j], hi = (float)qraw[mi][1][j];
      qf[mi][0][j] = (bf16_t)(lo * cl[mi][j] - hi * sl[mi][j]);
      qf[mi][1][j] = (bf16_t)(hi * chv[mi][j] + lo * shv[mi][j]);
    }

  // ---- K-rope in LDS: 256 threads x 4 rows each; octet pair d <-> d+32
  {
    int c_ = tid & 3;
#pragma unroll
    for (int rr = 0; rr < 4; ++rr) {
      int r_ = rr * 64 + (tid >> 2);
      int ks = sb * 256 + r_;
      int chl = ((c_ ^ (r_ & 7)) << 3), chh = (((c_ ^ 4) ^ (r_ & 7)) << 3);
      bf16x8 lo8 = *(bf16x8*)&Kl[r_ * 64 + chl];
      bf16x8 hi8 = *(bf16x8*)&Kl[r_ * 64 + chh];
      float kc_[8], ks_[8], kch[8], ksh[8];
      *(f32x4*)&kc_[0] = *(const f32x4*)&cosp[ks * DD + c_ * 8];
      *(f32x4*)&kc_[4] = *(const f32x4*)&cosp[ks * DD + c_ * 8 + 4];
      *(f32x4*)&kch[0] = *(const f32x4*)&cosp[ks * DD + c_ * 8 + 32];
      *(f32x4*)&kch[4] = *(const f32x4*)&cosp[ks * DD + c_ * 8 + 36];
      *(f32x4*)&ks_[0] = *(const f32x4*)&sinp[ks * DD + c_ * 8];
      *(f32x4*)&ks_[4] = *(const f32x4*)&sinp[ks * DD + c_ * 8 + 4];
      *(f32x4*)&ksh[0] = *(const f32x4*)&sinp[ks * DD + c_ * 8 + 32];
      *(f32x4*)&ksh[4] = *(const f32x4*)&sinp[ks * DD + c_ * 8 + 36];
      bf16x8 olo, ohi;
#pragma unroll
      for (int j = 0; j < 8; ++j) {
        float lo = (float)lo8[j], hi = (float)hi8[j];
        olo[j] = (bf16_t)(lo * kc_[j] - hi * ks_[j]);
        ohi[j] = (bf16_t)(hi * kch[j] + lo * ksh[j]);
      }
      *(bf16x8*)&Kl[r_ * 64 + chl] = olo;
      *(bf16x8*)&Kl[r_ * 64 + chh] = ohi;
    }
  }
  __syncthreads();  // roped K visible to all waves

  // ---- QK^T: full S[32q][256k] in registers (sc[2][16] f32x4 = 128 VGPR)
  f32x4 sc[2][16];
#pragma unroll
  for (int mi = 0; mi < 2; ++mi)
#pragma unroll
    for (int ni = 0; ni < 16; ++ni) sc[mi][ni] = f32x4{0.f, 0.f, 0.f, 0.f};
  __builtin_amdgcn_s_setprio(1);
#pragma unroll
  for (int kk = 0; kk < 2; ++kk) {
#pragma unroll
    for (int ni = 0; ni < 16; ++ni) {
      int row = ni * 16 + (ln & 15);
      int ch = (kk * 4 + (ln >> 4)) ^ (row & 7);
      bf16x8 kf = *(const bf16x8*)(&Kl[row * 64 + ch * 8]);
#pragma unroll
      for (int mi = 0; mi < 2; ++mi)
        sc[mi][ni] = __builtin_amdgcn_mfma_f32_16x16x32_bf16(qf[mi][kk], kf, sc[mi][ni], 0, 0, 0);
    }
  }
  __builtin_amdgcn_s_setprio(0);

  // ---- exact softmax (one pass; reduce in-lane 16, then across ln&15 lanes)
  float lr[2][4];
#pragma unroll
  for (int mi = 0; mi < 2; ++mi) {
#pragma unroll
    for (int r = 0; r < 4; ++r) {
      float mx = -1e30f;
#pragma unroll
      for (int ni = 0; ni < 16; ++ni) mx = fmaxf(mx, sc[mi][ni][r] * 0.125f);
#pragma unroll
      for (int d = 1; d < 16; d <<= 1) mx = fmaxf(mx, __shfl_xor(mx, d));
      float rs = 0.f;
#pragma unroll
      for (int ni = 0; ni < 16; ++ni) {
        float p = __expf(sc[mi][ni][r] * 0.125f - mx);
        sc[mi][ni][r] = p;
        rs += p;
      }
#pragma unroll
      for (int d = 1; d < 16; d <<= 1) rs += __shfl_xor(rs, d);
      lr[mi][r] = rs;
    }
  }

  // ---- PV: per 64-k chunk through per-wave P-LDS (no barriers; per-wave RAW via lgkm)
  f32x4 o[2][4] = {};
  bf16_t* P = Pl[wv];
#pragma unroll
  for (int kc = 0; kc < 4; ++kc) {
#pragma unroll
    for (int mi = 0; mi < 2; ++mi)
#pragma unroll
      for (int nq = 0; nq < 4; ++nq)
#pragma unroll
        for (int r = 0; r < 4; ++r) {
          int row = mi * 16 + ((ln >> 4) << 2) + r;
          int col = nq * 16 + (ln & 15);
          P[row * 64 + (col ^ ((row & 7) << 3))] = (bf16_t)sc[mi][kc * 4 + nq][r];
        }
    __builtin_amdgcn_s_setprio(1);
#pragma unroll
    for (int kk = 0; kk < 2; ++kk) {
      bf16x8 pf[2], vf[4];
#pragma unroll
      for (int mi = 0; mi < 2; ++mi) {
        int row = mi * 16 + (ln & 15);
        int ch = (kk * 4 + (ln >> 4)) ^ (row & 7);
        pf[mi] = *(const bf16x8*)(P + row * 64 + ch * 8);
      }
#pragma unroll
      for (int nd = 0; nd < 4; ++nd) {
        int d = nd * 16 + (ln & 15);
        int c = (kc * 8 + kk * 4 + (ln >> 4)) ^ ((d & 7) << 2);
        vf[nd] = *(const bf16x8*)(&Vl[d * 256 + c * 8]);
      }
#pragma unroll
      for (int mi = 0; mi < 2; ++mi)
#pragma unroll
        for (int nd = 0; nd < 4; ++nd)
          o[mi][nd] = __builtin_amdgcn_mfma_f32_16x16x32_bf16(pf[mi], vf[nd], o[mi][nd], 0, 0, 0);
    }
    __builtin_amdgcn_s_setprio(0);
  }

  // ---- epilogue: transpose o through freed Kl; vectorized gate+store
  __syncthreads();  // all waves past QK -> Kl safe to overwrite
  float* lrT = (float*)Pl[wv];
  if ((ln & 15) == 0) {
#pragma unroll
    for (int mi = 0; mi < 2; ++mi)
#pragma unroll
      for (int r = 0; r < 4; ++r)
        lrT[mi * 16 + ((ln >> 4) << 2) + r] = lr[mi][r];
  }
  float* T = (float*)Kl + wv * 2048;
#pragma unroll
  for (int mi = 0; mi < 2; ++mi)
#pragma unroll
    for (int nd = 0; nd < 4; ++nd)
#pragma unroll
      for (int r = 0; r < 4; ++r) {
        int row = mi * 16 + ((ln >> 4) << 2) + r;
        int col = nd * 16 + (ln & 15);
        int c = col >> 2;
        T[row * 64 + ((c ^ (row & 7)) << 2) + (col & 3)] = o[mi][nd][r];
      }
  {
    float inv = 1.f / lrT[erow];
    f32x4 ov[8];
#pragma unroll
    for (int j = 0; j < 8; ++j) {
      int c = ehf * 8 + j;
      ov[j] = *(const f32x4*)&T[erow * 64 + ((c ^ (erow & 7)) << 2)];
    }
    bf16_t* ap = AO + (size_t)em * EE + h * DD + ehf * 32;
#pragma unroll
    for (int i = 0; i < 4; ++i) {
      bf16x8 outv;
#pragma unroll
      for (int j2 = 0; j2 < 8; ++j2) {
        float gv = (float)gpre[i][j2];
        float sig = 1.f / (1.f + __expf(-gv));
        outv[j2] = (bf16_t)(ov[i * 2 + (j2 >> 2)][j2 & 3] * inv * sig);
      }
      *(bf16x8*)(ap + i * 8) = outv;
    }
  }
}

extern "C" void kernel_launch(void* const* d_in, const int* in_sizes, int n_in,
                              void* d_out, int out_size, void* d_ws, size_t ws_size,
                              hipStream_t stream) {
  const float* x = (const float*)d_in[0];
  const float* Wq = (const float*)d_in[1];
  const float* Wk = (const float*)d_in[2];
  const float* Wv = (const float*)d_in[3];
  const float* Wg = (const float*)d_in[4];
  const float* Wo = (const float*)d_in[5];
  const float* cosp = (const float*)d_in[6];
  const float* sinp = (const float*)d_in[7];
  float* out = (float*)d_out;

  char* ws = (char*)d_ws;
  bf16_t* XB = (bf16_t*)(ws);                       // 16MB: x bf16; reused as gated AO
  bf16_t* WT = (bf16_t*)(ws + (16ll << 20));        // 10MB: [5][1024][1024] W^T bf16 (q,k,v,g,o)
  bf16_t* QB = (bf16_t*)(ws + (26ll << 20));        // 16MB: Q (unroped)
  bf16_t* KB = (bf16_t*)(ws + (42ll << 20));        // 16MB: K (unroped)
  bf16_t* VT = (bf16_t*)(ws + (58ll << 20));        // 16MB: V transposed [B][H][D][S]
  bf16_t* GB = (bf16_t*)(ws + (74ll << 20));        // 16MB: gate
  bf16_t* AO = XB;                                  // gated attention output reuses XB region

  prep_kernel<<<9216, 256, 0, stream>>>(x, XB, Wq, Wk, Wv, Wg, Wo, WT);
  gemm_bt<0><<<dim3(MM / 128, 4 * EE / 128), 256, 0, stream>>>(XB, WT, QB, EE);
  attn_kernel<<<1024, 256, 0, stream>>>(QB, KB, VT, GB, cosp, sinp, AO);
  gemm_bt<1><<<dim3(MM / 128, EE / 128), 256, 0, stream>>>(AO, WT + (size_t)4 * EE * EE, out, EE);
}